// Round 8
// baseline (699.634 us; speedup 1.0000x reference)
//
#include <hip/hip_runtime.h>

typedef unsigned short u16;
typedef unsigned long long u64;
typedef __attribute__((ext_vector_type(8))) short bf16x8;
typedef __attribute__((ext_vector_type(4))) float f32x4;

#define MFMA16(a, b, c) __builtin_amdgcn_mfma_f32_16x16x32_bf16((a), (b), (c), 0, 0, 0)

// ---- problem sizes ----
#define TT 128
#define BB 128
#define IN_ 512
#define HH 512
#define G4 2048   // 4*H
#define OUTD 512
#define TB 16384  // T*B

#define AEXLD(p) __hip_atomic_load((p), __ATOMIC_RELAXED, __HIP_MEMORY_SCOPE_AGENT)

__device__ __forceinline__ u16 f2bf(float f) {
    union { float f; unsigned u; } v; v.f = f;
    unsigned r = v.u + 0x7FFFu + ((v.u >> 16) & 1u);
    return (u16)(r >> 16);
}
__device__ __forceinline__ float bf2f(u16 h) {
    union { unsigned u; float f; } v; v.u = ((unsigned)h) << 16; return v.f;
}
__device__ __forceinline__ float sigmoid_f(float x) { return 1.f / (1.f + __expf(-x)); }
__device__ __forceinline__ float tanh_f(float x) {
    float e = __expf(2.f * x);
    return 1.f - 2.f / (e + 1.f);
}

// ---- async global->LDS, 16B per lane (LDS dest linear: base + lane*16) ----
typedef unsigned __attribute__((address_space(1))) guint;
typedef unsigned __attribute__((address_space(3))) luint;
__device__ __forceinline__ void gll16(const u16* g, u16* l) {
    __builtin_amdgcn_global_load_lds((guint*)(void*)g, (luint*)(void*)l, 16, 0, 0);
}

// ---- fused prep: all bf16 converts + stacked bias + exchange-tag zero ----
// wih_cat rows 0..2047 = W_ih_f, 2048..4095 = W_ih_b.
__global__ void prep_kernel(
    const float* __restrict__ x,
    const float* __restrict__ Wihf, const float* __restrict__ Wihb,
    const float* __restrict__ Whhf, const float* __restrict__ Whhb,
    const float* __restrict__ Wlin,
    const float* __restrict__ bihf, const float* __restrict__ bhhf,
    const float* __restrict__ bihb, const float* __restrict__ bhhb,
    u16* __restrict__ x_bf, u16* __restrict__ wih_cat,
    u16* __restrict__ whhf_bf, u16* __restrict__ whhb_bf,
    u16* __restrict__ wlin_bf, float* __restrict__ bias_cat,
    uint4* __restrict__ exch) {
    const int i0 = blockIdx.x * blockDim.x + threadIdx.x;
    const int stride = gridDim.x * blockDim.x;
    #define CVT4(SRC, DST, N4, DOFF)                                        \
        for (int i = i0; i < (N4); i += stride) {                           \
            float4 v = ((const float4*)(SRC))[i];                           \
            ushort4 o;                                                      \
            o.x = f2bf(v.x); o.y = f2bf(v.y);                               \
            o.z = f2bf(v.z); o.w = f2bf(v.w);                               \
            ((ushort4*)(DST))[(DOFF) + i] = o;                              \
        }
    CVT4(x, x_bf, (TB * IN_) / 4, 0)
    CVT4(Wihf, wih_cat, (G4 * IN_) / 4, 0)
    CVT4(Wihb, wih_cat, (G4 * IN_) / 4, (G4 * IN_) / 4)
    CVT4(Whhf, whhf_bf, (G4 * HH) / 4, 0)
    CVT4(Whhb, whhb_bf, (G4 * HH) / 4, 0)
    CVT4(Wlin, wlin_bf, (OUTD * 2 * HH) / 4, 0)
    #undef CVT4
    for (int i = i0; i < G4; i += stride) {
        bias_cat[i]      = bihf[i] + bhhf[i];
        bias_cat[G4 + i] = bihb[i] + bhhb[i];
    }
    for (int i = i0; i < 65536; i += stride)   // 1 MB exchange: tags -> 0 (invalid)
        exch[i] = uint4{0u, 0u, 0u, 0u};
}

// ---- 128x128-tile bf16 MFMA GEMM (phase 3 only): C = A[M,K] * W[N,K]^T + bias ----
__global__ __launch_bounds__(256) void gemm_bias_kernel(
    const u16* __restrict__ A, const u16* __restrict__ W,
    const float* __restrict__ bias, void* __restrict__ Cout,
    int M, int N, int K, int out_is_bf16) {
    __shared__ __align__(16) u16 lA[128 * 64];   // linear (required by gll16)
    __shared__ __align__(16) u16 lB[128 * 64];
    const int tid = threadIdx.x;
    const int m0 = blockIdx.x * 128;
    const int n0 = blockIdx.y * 128;
    const int wave = tid >> 6, lane = tid & 63;
    const int wm = wave >> 1, wn = wave & 1;
    const int lrow = lane & 15, lq = lane >> 4;
    const int srow = lane >> 3, soff = (lane & 7) * 8;

    f32x4 acc[4][4] = {};

    for (int kc = 0; kc < K; kc += 64) {
        #pragma unroll
        for (int i = 0; i < 4; ++i) {
            int chunk = wave + i * 4;
            int row = chunk * 8 + srow;
            gll16(&A[(size_t)(m0 + row) * K + kc + soff], &lA[chunk * 512]);
            gll16(&W[(size_t)(n0 + row) * K + kc + soff], &lB[chunk * 512]);
        }
        __syncthreads();
        #pragma unroll
        for (int ks = 0; ks < 2; ++ks) {
            bf16x8 af[4], bfr[4];
            #pragma unroll
            for (int mf = 0; mf < 4; ++mf)
                af[mf] = *(const bf16x8*)(&lA[(wm * 64 + mf * 16 + lrow) * 64 + ks * 32 + lq * 8]);
            #pragma unroll
            for (int nf = 0; nf < 4; ++nf)
                bfr[nf] = *(const bf16x8*)(&lB[(wn * 64 + nf * 16 + lrow) * 64 + ks * 32 + lq * 8]);
            #pragma unroll
            for (int mf = 0; mf < 4; ++mf)
                #pragma unroll
                for (int nf = 0; nf < 4; ++nf)
                    acc[mf][nf] = MFMA16(af[mf], bfr[nf], acc[mf][nf]);
        }
        __syncthreads();
    }

    #pragma unroll
    for (int mf = 0; mf < 4; ++mf) {
        #pragma unroll
        for (int nf = 0; nf < 4; ++nf) {
            int row = m0 + wm * 64 + mf * 16 + lq * 4;
            int col = n0 + wn * 64 + nf * 16 + lrow;
            float bv = bias[col];
            f32x4 v = acc[mf][nf];
            #pragma unroll
            for (int r = 0; r < 4; ++r) {
                float val = v[r] + bv;
                if (out_is_bf16)
                    ((u16*)Cout)[(size_t)(row + r) * N + col] = f2bf(val);
                else
                    ((float*)Cout)[(size_t)(row + r) * N + col] = val;
            }
        }
    }
}

// ---- persistent fused recurrence + fused input GEMM ----
// 256 blocks, XCD-co-located groups: the 16 blocks of a (dir,bt) communication
// group share bx%8 (same XCD under default round-robin dispatch), localizing
// the exchange lines + shared x-tile in one L2. Mapping is bijective; if the
// XCD assumption is wrong this is a harmless relabeling.
// W_hh slice pinned in arch VGPRs ("v"), W_ih slice in AGPRs ("a") -- MFMA
// reads A/B from AGPR natively, splitting the unified 512-reg file.
// SCHEDULE (the r7 fix): xf loads + ALL xw MFMAs run BEFORE the poll -- they
// depend only on x and W_ih, so they overlap the producers' publish latency.
// The critical path is again poll->unpack->barA->hMFMA->sgate->barB->pointwise.
__global__ __attribute__((amdgpu_flat_work_group_size(256, 256),
                          amdgpu_waves_per_eu(1, 1)))
void lstm_persist_kernel(
    const u16* __restrict__ x_bf, const u16* __restrict__ wih_cat,
    const u16* __restrict__ whh_f, const u16* __restrict__ whh_b,
    const float* __restrict__ bias_cat, u16* __restrict__ hcat,
    u64* __restrict__ exch) {
    const int bx = blockIdx.x;
    const int slot = bx & 7;           // XCD slot
    const int jt  = (bx >> 3) & 15;    // member within group
    const int g   = slot + 8 * (bx >> 7);   // group 0..15
    const int dir = g >> 3;
    const int bt  = g & 7;
    const u16* __restrict__ whh = dir ? whh_b : whh_f;
    const int b0 = bt * 16;
    const int j0 = jt * 32;

    __shared__ __align__(16) u16 lh[16 * 520];   // h_prev tile [16 x 512], stride 520
    __shared__ float sgate[4][16][33];           // gate exchange [gate][b][j]

    const int tid = threadIdx.x;
    const int wave = tid >> 6, lane = tid & 63;
    const int lrow = lane & 15, lq = lane >> 4;

    // ---- preload W_hh ("v") and W_ih ("a") slices (gate `wave`, 32 rows x K=512) ----
    const u16* wrow_h = whh + ((size_t)wave * HH + j0) * HH;
    const u16* wrow_x = wih_cat + (size_t)dir * G4 * IN_ + ((size_t)wave * HH + j0) * IN_;
    bf16x8 w0[16], w1[16], u0[16], u1[16];
    #pragma unroll
    for (int kc = 0; kc < 16; ++kc) {
        w0[kc] = *(const bf16x8*)(&wrow_h[(size_t)lrow * HH + kc * 32 + lq * 8]);
        w1[kc] = *(const bf16x8*)(&wrow_h[(size_t)(16 + lrow) * HH + kc * 32 + lq * 8]);
        u0[kc] = *(const bf16x8*)(&wrow_x[(size_t)lrow * IN_ + kc * 32 + lq * 8]);
        u1[kc] = *(const bf16x8*)(&wrow_x[(size_t)(16 + lrow) * IN_ + kc * 32 + lq * 8]);
    }
    #pragma unroll
    for (int kc = 0; kc < 16; ++kc) {
        asm volatile("" : "+v"(w0[kc]), "+v"(w1[kc]));   // arch-VGPR pin
        asm volatile("" : "+a"(u0[kc]), "+a"(u1[kc]));   // AGPR pin
    }

    // pointwise cell ownership: thread -> (batch row bl, adjacent cols jj, jj+1)
    const int bl = tid >> 4;
    const int jj = (tid & 15) * 2;
    float cr0 = 0.f, cr1 = 0.f;

    // per-thread bias (gate g, cols j0+jj, j0+jj+1)
    float bs0[4], bs1[4];
    #pragma unroll
    for (int gg = 0; gg < 4; ++gg) {
        bs0[gg] = bias_cat[dir * G4 + gg * HH + j0 + jj];
        bs1[gg] = bias_cat[dir * G4 + gg * HH + j0 + jj + 1];
    }

    // producer-side exchange slot (u64 = adjacent cell pair)
    const size_t my_ex = ((size_t)dir * BB + b0 + bl) * 256 + (j0 >> 1) + (tid & 15);

    for (int s = 0; s < TT; ++s) {
        const int t = dir ? (TT - 1 - s) : s;

        // ---- pre-poll work: x fragments + the ENTIRE xw contribution ----
        // (independent of h; overlaps the producers' publish->visibility latency)
        const u16* xbase = x_bf + ((size_t)t * BB + b0 + lrow) * IN_ + lq * 8;
        bf16x8 xf[16];
        #pragma unroll
        for (int kc = 0; kc < 16; ++kc)
            xf[kc] = *(const bf16x8*)(xbase + kc * 32);

        f32x4 acc0 = {}, acc1 = {}, acc0b = {}, acc1b = {};
        #pragma unroll
        for (int kc = 0; kc < 16; kc += 2) {
            acc0  = MFMA16(xf[kc],     u0[kc],     acc0);
            acc1  = MFMA16(xf[kc],     u1[kc],     acc1);
            acc0b = MFMA16(xf[kc + 1], u0[kc + 1], acc0b);
            acc1b = MFMA16(xf[kc + 1], u1[kc + 1], acc1b);
        }

        if (s > 0) {
            // ---- single-RT handoff: 16 tagged u64s (coalesced), retry until valid ----
            const int p = (s - 1) & 1;
            const u64* ex = exch + ((size_t)(p * 2 + dir) * BB + b0) * 256 + tid;
            const u64 expect = ((u64)(unsigned)s << 48) | ((u64)(unsigned)s << 16);
            u64 v[16];
            for (;;) {
                #pragma unroll
                for (int i = 0; i < 16; ++i)
                    v[i] = AEXLD(ex + (size_t)i * 256);
                bool ok = true;
                #pragma unroll
                for (int i = 0; i < 16; ++i)
                    ok &= ((v[i] & 0xFFFF0000FFFF0000ull) == expect);
                if (ok) break;
            }
            // unpack to lh: cells (2*tid, 2*tid+1) of row i -> packed u32
            #pragma unroll
            for (int i = 0; i < 16; ++i)
                *(unsigned*)(&lh[i * 520 + tid * 2]) =
                    (unsigned)(v[i] & 0xffffu) | (unsigned)((v[i] >> 16) & 0xffff0000u);
            __syncthreads();   // bar A: lh ready

            #pragma unroll
            for (int kc = 0; kc < 16; kc += 2) {
                bf16x8 a0 = *(const bf16x8*)(&lh[lrow * 520 + kc * 32 + lq * 8]);
                bf16x8 a1 = *(const bf16x8*)(&lh[lrow * 520 + (kc + 1) * 32 + lq * 8]);
                acc0  = MFMA16(a0, w0[kc], acc0);
                acc1  = MFMA16(a0, w1[kc], acc1);
                acc0b = MFMA16(a1, w0[kc + 1], acc0b);
                acc1b = MFMA16(a1, w1[kc + 1], acc1b);
            }
        }
        acc0 += acc0b;
        acc1 += acc1b;

        // gates -> LDS (D layout: m = lq*4+r batch-local, n in {lrow, 16+lrow})
        #pragma unroll
        for (int r = 0; r < 4; ++r) {
            sgate[wave][lq * 4 + r][lrow]      = acc0[r];
            sgate[wave][lq * 4 + r][16 + lrow] = acc1[r];
        }
        __syncthreads();   // bar B: gates ready (also protects lh vs next fill)

        // pointwise: 2 adjacent cells per thread, bias from regs, c in regs
        float gi0 = sgate[0][bl][jj]     + bs0[0];
        float gf0 = sgate[1][bl][jj]     + bs0[1];
        float gg0 = sgate[2][bl][jj]     + bs0[2];
        float go0 = sgate[3][bl][jj]     + bs0[3];
        float gi1 = sgate[0][bl][jj + 1] + bs1[0];
        float gf1 = sgate[1][bl][jj + 1] + bs1[1];
        float gg1 = sgate[2][bl][jj + 1] + bs1[2];
        float go1 = sgate[3][bl][jj + 1] + bs1[3];

        float c0 = sigmoid_f(gf0) * cr0 + sigmoid_f(gi0) * tanh_f(gg0);
        float c1 = sigmoid_f(gf1) * cr1 + sigmoid_f(gi1) * tanh_f(gg1);
        cr0 = c0; cr1 = c1;
        float h0 = sigmoid_f(go0) * tanh_f(c0);
        float h1 = sigmoid_f(go1) * tanh_f(c1);

        // publish FIRST (unblocks consumers), then hcat for phase 3
        unsigned hb0 = (unsigned)f2bf(h0), hb1 = (unsigned)f2bf(h1);
        unsigned tagv = (unsigned)(s + 1) << 16;
        u64 pv = (u64)(tagv | hb0) | ((u64)(tagv | hb1) << 32);
        __hip_atomic_store(exch + (size_t)((s & 1) * 2) * BB * 256 + my_ex, pv,
                           __ATOMIC_RELAXED, __HIP_MEMORY_SCOPE_AGENT);

        *(unsigned*)(hcat + ((size_t)t * BB + b0 + bl) * (2 * HH) + dir * HH + j0 + jj) =
            hb0 | (hb1 << 16);
    }
}

// ---- workspace layout (bytes) ----
#define OFF_XBF    ((size_t)0)                             // 16,777,216
#define OFF_WIH    (OFF_XBF  + (size_t)TB * IN_ * 2)       // stacked W_ih: 4,194,304
#define OFF_WHHF   (OFF_WIH  + (size_t)2 * G4 * IN_ * 2)
#define OFF_WHHB   (OFF_WHHF + (size_t)G4 * HH * 2)
#define OFF_WLIN   (OFF_WHHB + (size_t)G4 * HH * 2)
#define OFF_BIAS   (OFF_WLIN + (size_t)OUTD * 2 * HH * 2)  // stacked bias: 16,384
#define OFF_HCAT   (OFF_BIAS + (size_t)2 * G4 * 4)         // 33,554,432
#define OFF_EXCH   (OFF_HCAT + (size_t)TB * 2 * HH * 2)    // tagged ping-pong h: 1 MB
#define WS_NEED    (OFF_EXCH + (size_t)2 * 2 * BB * HH * 4)

extern "C" void kernel_launch(void* const* d_in, const int* in_sizes, int n_in,
                              void* d_out, int out_size, void* d_ws, size_t ws_size,
                              hipStream_t stream) {
    (void)in_sizes; (void)n_in; (void)out_size;
    if (ws_size < WS_NEED) return;

    const float* x    = (const float*)d_in[0];
    const float* Wihf = (const float*)d_in[1];
    const float* Whhf = (const float*)d_in[2];
    const float* bihf = (const float*)d_in[3];
    const float* bhhf = (const float*)d_in[4];
    const float* Wihb = (const float*)d_in[5];
    const float* Whhb = (const float*)d_in[6];
    const float* bihb = (const float*)d_in[7];
    const float* bhhb = (const float*)d_in[8];
    const float* Wlin = (const float*)d_in[9];
    const float* blin = (const float*)d_in[10];
    float* out = (float*)d_out;

    char* ws = (char*)d_ws;
    u16* x_bf     = (u16*)(ws + OFF_XBF);
    u16* wih_cat  = (u16*)(ws + OFF_WIH);
    u16* whhf_bf  = (u16*)(ws + OFF_WHHF);
    u16* whhb_bf  = (u16*)(ws + OFF_WHHB);
    u16* wlin_bf  = (u16*)(ws + OFF_WLIN);
    float* bias_cat = (float*)(ws + OFF_BIAS);
    u16* hcat = (u16*)(ws + OFF_HCAT);
    u64* exch = (u64*)(ws + OFF_EXCH);

    // prep: all converts + stacked bias + exchange-tag zero, ONE launch
    prep_kernel<<<1024, 256, 0, stream>>>(x, Wihf, Wihb, Whhf, Whhb, Wlin,
                                          bihf, bhhf, bihb, bhhb,
                                          x_bf, wih_cat, whhf_bf, whhb_bf, wlin_bf,
                                          bias_cat, (uint4*)exch);

    // phases 1+2 fused: persistent kernel computes xw on the fly and runs all
    // 128 recurrent steps, both dirs. Plain launch: 256 blocks <= 256 CUs at
    // 1 block/CU (waves_per_eu 1) -> co-resident by capacity.
    lstm_persist_kernel<<<256, 256, 0, stream>>>(x_bf, wih_cat, whhf_bf, whhb_bf,
                                                 bias_cat, hcat, exch);

    // phase 3: out = hcat @ W_lin^T + b_lin, fp32 out
    gemm_bias_kernel<<<dim3(TB / 128, OUTD / 128), 256, 0, stream>>>(
        hcat, wlin_bf, blin, out, TB, OUTD, 2 * HH, 0);
}

// Round 9
// 621.099 us; speedup vs baseline: 1.1264x; 1.1264x over previous
//
#include <hip/hip_runtime.h>

typedef unsigned short u16;
typedef unsigned long long u64;
typedef __attribute__((ext_vector_type(8))) short bf16x8;
typedef __attribute__((ext_vector_type(4))) float f32x4;

#define MFMA16(a, b, c) __builtin_amdgcn_mfma_f32_16x16x32_bf16((a), (b), (c), 0, 0, 0)

// ---- problem sizes ----
#define TT 128
#define BB 128
#define IN_ 512
#define HH 512
#define G4 2048   // 4*H
#define OUTD 512
#define TB 16384  // T*B

#define AEXLD(p) __hip_atomic_load((p), __ATOMIC_RELAXED, __HIP_MEMORY_SCOPE_AGENT)

__device__ __forceinline__ u16 f2bf(float f) {
    union { float f; unsigned u; } v; v.f = f;
    unsigned r = v.u + 0x7FFFu + ((v.u >> 16) & 1u);
    return (u16)(r >> 16);
}
__device__ __forceinline__ float bf2f(u16 h) {
    union { unsigned u; float f; } v; v.u = ((unsigned)h) << 16; return v.f;
}
__device__ __forceinline__ float sigmoid_f(float x) { return 1.f / (1.f + __expf(-x)); }
__device__ __forceinline__ float tanh_f(float x) {
    float e = __expf(2.f * x);
    return 1.f - 2.f / (e + 1.f);
}

// ---- async global->LDS, 16B per lane (LDS dest = wave-uniform base + lane*16) ----
typedef unsigned __attribute__((address_space(1))) guint;
typedef unsigned __attribute__((address_space(3))) luint;
__device__ __forceinline__ void gll16(const u16* g, u16* l) {
    __builtin_amdgcn_global_load_lds((guint*)(void*)g, (luint*)(void*)l, 16, 0, 0);
}

// ---- fused prep: all bf16 converts + stacked bias + exchange-tag zero ----
// wih_cat rows 0..2047 = W_ih_f, 2048..4095 = W_ih_b (merged phase-1 GEMM).
__global__ void prep_kernel(
    const float* __restrict__ x,
    const float* __restrict__ Wihf, const float* __restrict__ Wihb,
    const float* __restrict__ Whhf, const float* __restrict__ Whhb,
    const float* __restrict__ Wlin,
    const float* __restrict__ bihf, const float* __restrict__ bhhf,
    const float* __restrict__ bihb, const float* __restrict__ bhhb,
    u16* __restrict__ x_bf, u16* __restrict__ wih_cat,
    u16* __restrict__ whhf_bf, u16* __restrict__ whhb_bf,
    u16* __restrict__ wlin_bf, float* __restrict__ bias_cat,
    uint4* __restrict__ exch) {
    const int i0 = blockIdx.x * blockDim.x + threadIdx.x;
    const int stride = gridDim.x * blockDim.x;
    #define CVT4(SRC, DST, N4, DOFF)                                        \
        for (int i = i0; i < (N4); i += stride) {                           \
            float4 v = ((const float4*)(SRC))[i];                           \
            ushort4 o;                                                      \
            o.x = f2bf(v.x); o.y = f2bf(v.y);                               \
            o.z = f2bf(v.z); o.w = f2bf(v.w);                               \
            ((ushort4*)(DST))[(DOFF) + i] = o;                              \
        }
    CVT4(x, x_bf, (TB * IN_) / 4, 0)
    CVT4(Wihf, wih_cat, (G4 * IN_) / 4, 0)
    CVT4(Wihb, wih_cat, (G4 * IN_) / 4, (G4 * IN_) / 4)
    CVT4(Whhf, whhf_bf, (G4 * HH) / 4, 0)
    CVT4(Whhb, whhb_bf, (G4 * HH) / 4, 0)
    CVT4(Wlin, wlin_bf, (OUTD * 2 * HH) / 4, 0)
    #undef CVT4
    for (int i = i0; i < G4; i += stride) {
        bias_cat[i]      = bihf[i] + bhhf[i];
        bias_cat[G4 + i] = bihb[i] + bhhb[i];
    }
    for (int i = i0; i < 65536; i += stride)   // 1 MB exchange: tags -> 0 (invalid)
        exch[i] = uint4{0u, 0u, 0u, 0u};
}

// ---- 128x128-tile bf16 MFMA GEMM: C[M,N] = A[M,K] * W[N,K]^T + bias[N] ----
// gll16 staging into LINEAR [128][64]-short LDS + BOTH-SIDES XOR swizzle
// (T2/m201 rule): gll16's dest must be linear, so the swizzle is applied to
// the global SOURCE slot (slot^row&7) and the same XOR on the ds_read address.
// This spreads the 8 16B-slots uniformly (8 lanes/slot = structural optimum
// for ds_read_b128); the r5 linear version had slot=lq only (16 lanes/slot,
// 2x LDS-read cost -> 386 TF). 
__global__ __launch_bounds__(256) void gemm_bias_kernel(
    const u16* __restrict__ A, const u16* __restrict__ W,
    const float* __restrict__ bias, void* __restrict__ Cout,
    int M, int N, int K, int out_is_bf16) {
    __shared__ __align__(16) u16 lA[128 * 64];
    __shared__ __align__(16) u16 lB[128 * 64];
    const int tid = threadIdx.x;
    const int m0 = blockIdx.x * 128;
    const int n0 = blockIdx.y * 128;
    const int wave = tid >> 6, lane = tid & 63;
    const int wm = wave >> 1, wn = wave & 1;
    const int lrow = lane & 15, lq = lane >> 4;
    const int srow = lane >> 3;                    // row-within-8 of staging
    const int ssw  = (lane & 7) ^ srow;            // swizzled source 16B-slot

    f32x4 acc[4][4] = {};

    for (int kc = 0; kc < K; kc += 64) {
        // stage A,B: chunk = 8 rows x 128B; LDS linear, source slot pre-swizzled
        #pragma unroll
        for (int i = 0; i < 4; ++i) {
            int chunk = wave + i * 4;              // 0..15
            int row = chunk * 8 + srow;            // row&7 == srow
            gll16(&A[(size_t)(m0 + row) * K + kc + ssw * 8], &lA[chunk * 512]);
            gll16(&W[(size_t)(n0 + row) * K + kc + ssw * 8], &lB[chunk * 512]);
        }
        __syncthreads();
        #pragma unroll
        for (int ks = 0; ks < 2; ++ks) {
            bf16x8 af[4], bfr[4];
            #pragma unroll
            for (int mf = 0; mf < 4; ++mf) {
                int row = wm * 64 + mf * 16 + lrow;
                int c16 = (ks * 4 + lq) ^ (row & 7);   // read-side same XOR
                af[mf] = *(const bf16x8*)(&lA[row * 64 + c16 * 8]);
            }
            #pragma unroll
            for (int nf = 0; nf < 4; ++nf) {
                int row = wn * 64 + nf * 16 + lrow;
                int c16 = (ks * 4 + lq) ^ (row & 7);
                bfr[nf] = *(const bf16x8*)(&lB[row * 64 + c16 * 8]);
            }
            #pragma unroll
            for (int mf = 0; mf < 4; ++mf)
                #pragma unroll
                for (int nf = 0; nf < 4; ++nf)
                    acc[mf][nf] = MFMA16(af[mf], bfr[nf], acc[mf][nf]);
        }
        __syncthreads();
    }

    #pragma unroll
    for (int mf = 0; mf < 4; ++mf) {
        #pragma unroll
        for (int nf = 0; nf < 4; ++nf) {
            int row = m0 + wm * 64 + mf * 16 + lq * 4;
            int col = n0 + wn * 64 + nf * 16 + lrow;
            float bv = bias[col];
            f32x4 v = acc[mf][nf];
            #pragma unroll
            for (int r = 0; r < 4; ++r) {
                float val = v[r] + bv;
                if (out_is_bf16)
                    ((u16*)Cout)[(size_t)(row + r) * N + col] = f2bf(val);
                else
                    ((float*)Cout)[(size_t)(row + r) * N + col] = val;
            }
        }
    }
}

// ---- persistent fused recurrence (r5-exact structure, verified 406 us) ----
// grid = 256 blocks: bx = dir*128 + bt*16 + jt. Block owns gates tile
// [16 batch x (4 gates x 32 j)]; W_hh slice + c-state pinned in registers.
// Handoff: self-validating tagged u64 cells (tag16|h_bf16 per u32), relaxed
// agent-scope atomics only; coalesced 16-u64 volley into LDS; ping-pong by
// step parity; tag mismatch only ever causes a retry (ABA-safe, see r3).
__global__ __launch_bounds__(256, 1) void lstm_persist_kernel(
    const u16* __restrict__ xw, const u16* __restrict__ whh_f,
    const u16* __restrict__ whh_b, u16* __restrict__ hcat,
    u64* __restrict__ exch) {
    const int bx = blockIdx.x;
    const int dir = bx >> 7;
    const int bt = (bx >> 4) & 7;
    const int jt = bx & 15;
    const u16* __restrict__ whh = dir ? whh_b : whh_f;
    const int b0 = bt * 16;
    const int j0 = jt * 32;

    __shared__ __align__(16) u16 lh[16 * 520];   // h_prev tile [16 x 512], stride 520
    __shared__ float sgate[4][16][33];           // gate exchange [gate][b][j]

    const int tid = threadIdx.x;
    const int wave = tid >> 6, lane = tid & 63;
    const int lrow = lane & 15, lq = lane >> 4;

    // ---- preload this wave's W_hh slice (gate `wave`, 32 rows x K=512) into regs ----
    const u16* wrow = whh + ((size_t)wave * HH + j0) * HH;
    bf16x8 w0[16], w1[16];
    #pragma unroll
    for (int kc = 0; kc < 16; ++kc) {
        w0[kc] = *(const bf16x8*)(&wrow[(size_t)lrow * HH + kc * 32 + lq * 8]);
        w1[kc] = *(const bf16x8*)(&wrow[(size_t)(16 + lrow) * HH + kc * 32 + lq * 8]);
    }
    #pragma unroll
    for (int kc = 0; kc < 16; ++kc)
        asm volatile("" : "+v"(w0[kc]), "+v"(w1[kc]));

    // pointwise cell ownership: thread -> (batch row bl, adjacent cols jj, jj+1)
    const int bl = tid >> 4;
    const int jj = (tid & 15) * 2;
    float cr0 = 0.f, cr1 = 0.f;

    // producer-side exchange slot (u64 = adjacent cell pair)
    const size_t my_ex = ((size_t)dir * BB + b0 + bl) * 256 + (j0 >> 1) + (tid & 15);

    for (int s = 0; s < TT; ++s) {
        const int t = dir ? (TT - 1 - s) : s;

        // prefetch xw for this thread's 2 cells (4 gates, u32 each) before the wait
        const u16* xrow = xw + ((size_t)t * BB + b0 + bl) * (2 * G4) + dir * G4 + j0 + jj;
        unsigned xg[4];
        #pragma unroll
        for (int g = 0; g < 4; ++g)
            xg[g] = *(const unsigned*)(xrow + (size_t)g * HH);

        f32x4 acc0 = {}, acc1 = {}, acc0b = {}, acc1b = {};
        if (s > 0) {
            // ---- single-RT handoff: load 16 tagged u64s (coalesced), retry until valid ----
            const int p = (s - 1) & 1;
            const u64* ex = exch + ((size_t)(p * 2 + dir) * BB + b0) * 256 + tid;
            const u64 expect = ((u64)(unsigned)s << 48) | ((u64)(unsigned)s << 16);
            u64 v[16];
            for (;;) {
                #pragma unroll
                for (int i = 0; i < 16; ++i)
                    v[i] = AEXLD(ex + (size_t)i * 256);
                bool ok = true;
                #pragma unroll
                for (int i = 0; i < 16; ++i)
                    ok &= ((v[i] & 0xFFFF0000FFFF0000ull) == expect);
                if (ok) break;
            }
            // unpack to lh: cells (2*tid, 2*tid+1) of row i -> packed u32
            #pragma unroll
            for (int i = 0; i < 16; ++i)
                *(unsigned*)(&lh[i * 520 + tid * 2]) =
                    (unsigned)(v[i] & 0xffffu) | (unsigned)((v[i] >> 16) & 0xffff0000u);
            __syncthreads();   // bar A: lh ready

            #pragma unroll
            for (int kc = 0; kc < 16; kc += 2) {
                bf16x8 a0 = *(const bf16x8*)(&lh[lrow * 520 + kc * 32 + lq * 8]);
                bf16x8 a1 = *(const bf16x8*)(&lh[lrow * 520 + (kc + 1) * 32 + lq * 8]);
                acc0  = MFMA16(a0, w0[kc], acc0);
                acc1  = MFMA16(a0, w1[kc], acc1);
                acc0b = MFMA16(a1, w0[kc + 1], acc0b);
                acc1b = MFMA16(a1, w1[kc + 1], acc1b);
            }
            acc0 += acc0b;
            acc1 += acc1b;
        }

        // gates -> LDS (D layout: m = lq*4+r batch-local, n in {lrow, 16+lrow})
        #pragma unroll
        for (int r = 0; r < 4; ++r) {
            sgate[wave][lq * 4 + r][lrow]      = acc0[r];
            sgate[wave][lq * 4 + r][16 + lrow] = acc1[r];
        }
        __syncthreads();   // bar B: gates ready (also protects lh vs next fill)

        // pointwise: 2 adjacent cells per thread, c in registers
        float gi0 = sgate[0][bl][jj]     + bf2f((u16)(xg[0] & 0xffffu));
        float gf0 = sgate[1][bl][jj]     + bf2f((u16)(xg[1] & 0xffffu));
        float gg0 = sgate[2][bl][jj]     + bf2f((u16)(xg[2] & 0xffffu));
        float go0 = sgate[3][bl][jj]     + bf2f((u16)(xg[3] & 0xffffu));
        float gi1 = sgate[0][bl][jj + 1] + bf2f((u16)(xg[0] >> 16));
        float gf1 = sgate[1][bl][jj + 1] + bf2f((u16)(xg[1] >> 16));
        float gg1 = sgate[2][bl][jj + 1] + bf2f((u16)(xg[2] >> 16));
        float go1 = sgate[3][bl][jj + 1] + bf2f((u16)(xg[3] >> 16));

        float c0 = sigmoid_f(gf0) * cr0 + sigmoid_f(gi0) * tanh_f(gg0);
        float c1 = sigmoid_f(gf1) * cr1 + sigmoid_f(gi1) * tanh_f(gg1);
        cr0 = c0; cr1 = c1;
        float h0 = sigmoid_f(go0) * tanh_f(c0);
        float h1 = sigmoid_f(go1) * tanh_f(c1);

        // publish: ONE tagged u64 (self-validating, relaxed agent scope)
        unsigned hb0 = (unsigned)f2bf(h0), hb1 = (unsigned)f2bf(h1);
        unsigned tagv = (unsigned)(s + 1) << 16;
        u64 pv = (u64)(tagv | hb0) | ((u64)(tagv | hb1) << 32);
        __hip_atomic_store(exch + (size_t)((s & 1) * 2) * BB * 256 + my_ex, pv,
                           __ATOMIC_RELAXED, __HIP_MEMORY_SCOPE_AGENT);

        // hcat for phase 3 (normal cached store; off the critical path)
        *(unsigned*)(hcat + ((size_t)t * BB + b0 + bl) * (2 * HH) + dir * HH + j0 + jj) =
            hb0 | (hb1 << 16);
    }
}

// ---- workspace layout (bytes) ----
#define OFF_XBF    ((size_t)0)                             // 16,777,216
#define OFF_WIH    (OFF_XBF  + (size_t)TB * IN_ * 2)       // stacked W_ih: 4,194,304
#define OFF_WHHF   (OFF_WIH  + (size_t)2 * G4 * IN_ * 2)
#define OFF_WHHB   (OFF_WHHF + (size_t)G4 * HH * 2)
#define OFF_WLIN   (OFF_WHHB + (size_t)G4 * HH * 2)
#define OFF_BIAS   (OFF_WLIN + (size_t)OUTD * 2 * HH * 2)  // stacked bias: 16,384
#define OFF_XW     (OFF_BIAS + (size_t)2 * G4 * 4)         // [TB][4096]: 134,217,728
#define OFF_HCAT   (OFF_XW   + (size_t)TB * 2 * G4 * 2)    // 33,554,432
#define OFF_EXCH   (OFF_HCAT + (size_t)TB * 2 * HH * 2)    // tagged ping-pong h: 1 MB
#define WS_NEED    (OFF_EXCH + (size_t)2 * 2 * BB * HH * 4)

extern "C" void kernel_launch(void* const* d_in, const int* in_sizes, int n_in,
                              void* d_out, int out_size, void* d_ws, size_t ws_size,
                              hipStream_t stream) {
    (void)in_sizes; (void)n_in; (void)out_size;
    if (ws_size < WS_NEED) return;

    const float* x    = (const float*)d_in[0];
    const float* Wihf = (const float*)d_in[1];
    const float* Whhf = (const float*)d_in[2];
    const float* bihf = (const float*)d_in[3];
    const float* bhhf = (const float*)d_in[4];
    const float* Wihb = (const float*)d_in[5];
    const float* Whhb = (const float*)d_in[6];
    const float* bihb = (const float*)d_in[7];
    const float* bhhb = (const float*)d_in[8];
    const float* Wlin = (const float*)d_in[9];
    const float* blin = (const float*)d_in[10];
    float* out = (float*)d_out;

    char* ws = (char*)d_ws;
    u16* x_bf     = (u16*)(ws + OFF_XBF);
    u16* wih_cat  = (u16*)(ws + OFF_WIH);
    u16* whhf_bf  = (u16*)(ws + OFF_WHHF);
    u16* whhb_bf  = (u16*)(ws + OFF_WHHB);
    u16* wlin_bf  = (u16*)(ws + OFF_WLIN);
    float* bias_cat = (float*)(ws + OFF_BIAS);
    u16* xw   = (u16*)(ws + OFF_XW);
    u16* hcat = (u16*)(ws + OFF_HCAT);
    u64* exch = (u64*)(ws + OFF_EXCH);

    // prep: all converts + stacked bias + exchange-tag zero, ONE launch
    prep_kernel<<<1024, 256, 0, stream>>>(x, Wihf, Wihb, Whhf, Whhb, Wlin,
                                          bihf, bhhf, bihb, bhhb,
                                          x_bf, wih_cat, whhf_bf, whhb_bf, wlin_bf,
                                          bias_cat, (uint4*)exch);

    // phase 1: xw = x @ [W_ih_f; W_ih_b]^T + bias_cat, bf16 out, ONE GEMM (N=4096)
    gemm_bias_kernel<<<dim3(TB / 128, (2 * G4) / 128), 256, 0, stream>>>(
        x_bf, wih_cat, bias_cat, xw, TB, 2 * G4, IN_, 1);

    // phase 2: persistent kernel, all 128 recurrent steps, both dirs.
    // Plain launch: 256 blocks <= 256 CUs at 1 block/CU -> co-resident by capacity.
    lstm_persist_kernel<<<256, 256, 0, stream>>>(xw, whhf_bf, whhb_bf, hcat, exch);

    // phase 3: out = hcat @ W_lin^T + b_lin, fp32 out
    gemm_bias_kernel<<<dim3(TB / 128, OUTD / 128), 256, 0, stream>>>(
        hcat, wlin_bf, blin, out, TB, OUTD, 2 * HH, 0);
}